// Round 11
// baseline (181.410 us; speedup 1.0000x reference)
//
#include <hip/hip_runtime.h>
#include <hip/hip_bf16.h>

// B=8, T=1024, D=128, TEMP=0.1, WEIGHT=1.0. 56 ordered pairs (i,j), i!=j.
// p~ = exp2(dot(SQDS*q, SQDS*k)) ; g[s] = exp2(-|e_s|^2*NSCALE) (row-const dropped)
// nn_t = (sum p~ V')/L, V' = g*SQDS-scaled e2, L = sum p~ g (via [g; g*sp] MFMA)
// phase2: pred = (sum p~2 g2 sp)/(sum p~2 g2);  loss = mean (pred - sp_t)^2
//
// R11: barrier-free register pipeline. NO LDS, 1-wave blocks (grid 1792).
// Per s-32 tile: prefetch next tile's 18 chunks into the ping register set
// (global_load_dwordx4), sched_barrier(0), compute current from pong set ->
// compiler emits non-zero vmcnt waits (loads in flight across the whole
// iteration; the AITER pattern the barrier structure couldn't express).
// Ping-pong bodies are explicitly duplicated so buffer indices are
// compile-time (dynamic-indexed register arrays would spill to scratch).
// ZERO-C trick: first MFMA of each chain consumes a persistent zero vector
// (kills 64 per-iter acc-init VALU). Transposed-S + c2b + gsp-MFMA carried
// from R8-R10 (verified). WATCH: WRITE_SIZE ~28KB. If MBs -> spill.

#define T_ 1024
#define D_ 128
#define NPAIR 56
#define NSCALE 0.11271055006945026f   // (1/12.8)*log2(e)
#define SQDS 0.474785316f             // sqrt((2/12.8)*log2(e))

typedef short short8 __attribute__((ext_vector_type(8)));
typedef unsigned short u16x8 __attribute__((ext_vector_type(8)));
typedef float f32x16 __attribute__((ext_vector_type(16)));

#define BATCH_STRIDE 131072  // shorts per batch in ebfF/ebfT (256 chunks * 512)
#define GSP_STRIDE 32768     // shorts per batch in gspF (64 chunks * 512)

__device__ __forceinline__ unsigned short f2bf(float f) {
  unsigned u = __float_as_uint(f);
  u += 0x7fff + ((u >> 16) & 1);  // RNE
  return (unsigned short)(u >> 16);
}
__device__ __forceinline__ float bf2f(unsigned short v) {
  return __uint_as_float(((unsigned)v) << 16);
}
__device__ __forceinline__ unsigned packbf(float a, float b) {
  __hip_bfloat162 h = __float22bfloat162_rn(float2{a, b});
  unsigned u; __builtin_memcpy(&u, &h, 4); return u;
}
__device__ __forceinline__ short8 mk8(unsigned a, unsigned b, unsigned c, unsigned d) {
  union { unsigned u[4]; short8 s; } x;
  x.u[0] = a; x.u[1] = b; x.u[2] = c; x.u[3] = d; return x.s;
}
__device__ __forceinline__ float waveSum(float v) {
#pragma unroll
  for (int k = 32; k >= 1; k >>= 1) v += __shfl_xor(v, k, 64);
  return v;
}

// C-layout (col=lane&31, row=(rg&3)+8*(rg>>2)+4*lh) -> B-operand chunks for a
// 32-wide k-range. Input: 8 packed dwords d[k]=(rows 2k,2k+1). Output 2 chunks.
__device__ __forceinline__ void c2b(const unsigned* d, int lh, short8* b0, short8* b1) {
  unsigned s0 = lh ? d[0] : d[2];
  unsigned s1 = lh ? d[1] : d[3];
  unsigned s2 = lh ? d[4] : d[6];
  unsigned s3 = lh ? d[5] : d[7];
  unsigned r0 = (unsigned)__shfl_xor((int)s0, 32, 64);
  unsigned r1 = (unsigned)__shfl_xor((int)s1, 32, 64);
  unsigned r2 = (unsigned)__shfl_xor((int)s2, 32, 64);
  unsigned r3 = (unsigned)__shfl_xor((int)s3, 32, 64);
  *b0 = (lh == 0) ? mk8(d[0], d[1], r0, r1) : mk8(r0, r1, d[2], d[3]);
  *b1 = (lh == 0) ? mk8(d[4], d[5], r2, r3) : mk8(r2, r3, d[6], d[7]);
}

// ---- convert: fp32 -> SQDS-scaled bf16 fragA (ebfF), g*SQDS-scaled fragT
//      (ebfT), gsp A-frags ([g; g*sp]), steps, ws init ----
__global__ __launch_bounds__(256) void convert_kernel(
    const float* __restrict__ embs, const int* __restrict__ fi,
    const int* __restrict__ vl, unsigned short* __restrict__ ebfF,
    unsigned short* __restrict__ ebfT, unsigned short* __restrict__ gspF,
    float* __restrict__ steps, float* __restrict__ acc, unsigned* __restrict__ cnt) {
  __shared__ unsigned short tileS[32 * 136];
  __shared__ float psum[32][8];
  __shared__ float g_sh[32], sp_sh[32];
  const int b = blockIdx.x >> 5;
  const int t0 = (blockIdx.x & 31) * 32;
  const int tid = threadIdx.x;
  const int row = tid >> 3, seg = tid & 7;

  if (blockIdx.x == 0 && tid == 0) { acc[0] = 0.f; cnt[0] = 0u; }

  const float* src = embs + (size_t)(b * T_ + t0 + row) * D_ + seg * 16;
  float4 g[4];
#pragma unroll
  for (int k = 0; k < 4; k++) g[k] = ((const float4*)src)[k];
  float s = 0.f;
  unsigned short v[16];
#pragma unroll
  for (int k = 0; k < 4; k++) {
    s += g[k].x * g[k].x + g[k].y * g[k].y + g[k].z * g[k].z + g[k].w * g[k].w;
    v[k * 4 + 0] = f2bf(g[k].x * SQDS); v[k * 4 + 1] = f2bf(g[k].y * SQDS);
    v[k * 4 + 2] = f2bf(g[k].z * SQDS); v[k * 4 + 3] = f2bf(g[k].w * SQDS);
  }
  psum[row][seg] = s;

  unsigned short* dstA = ebfF + (size_t)b * BATCH_STRIDE + (size_t)((t0 >> 5) * 8 + seg) * 512;
  *(u16x8*)(dstA + row * 8) = *(const u16x8*)&v[0];
  *(u16x8*)(dstA + (32 + row) * 8) = *(const u16x8*)&v[8];

  *(u16x8*)&tileS[row * 136 + seg * 16] = *(const u16x8*)&v[0];
  *(u16x8*)&tileS[row * 136 + seg * 16 + 8] = *(const u16x8*)&v[8];
  __syncthreads();

  if (tid < 32) {
    float t = 0.f;
#pragma unroll
    for (int k = 0; k < 8; k++) t += psum[tid][k];
    int gr = b * T_ + t0 + tid;
    float sp = (float)fi[gr] / (float)vl[b];
    steps[gr] = sp;
    sp_sh[tid] = sp;
    g_sh[tid] = __builtin_amdgcn_exp2f(-t * NSCALE);
  }
  __syncthreads();

  const int c8 = tid >> 5;
  const int d0t = (c8 & 3) * 32, sc = c8 >> 2;
  const int chunk = (d0t >> 5) * 64 + (t0 >> 4) + sc;
  unsigned short* dstT = ebfT + (size_t)b * BATCH_STRIDE + (size_t)chunk * 512;
  const int dd = d0t + (tid & 31);
#pragma unroll
  for (int half = 0; half < 2; half++) {
    const int lane = half * 32 + (tid & 31);
    const int sl = sc * 16 + half * 8;
    u16x8 w;
#pragma unroll
    for (int jj = 0; jj < 8; jj++)
      w[jj] = f2bf(bf2f(tileS[(sl + jj) * 136 + dd]) * g_sh[sl + jj]);
    *(u16x8*)(dstT + lane * 8) = w;
  }

  // gsp A-frags: rows m=0 -> g, m=1 -> g*sp, rest 0
  for (int idx = tid; idx < 1024; idx += 256) {
    int cchunk = idx >> 9, within = idx & 511;
    int lane = within >> 3, e = within & 7;
    int m = lane & 31, kh = lane >> 5;
    int sl = cchunk * 16 + kh * 8 + e;
    unsigned short val = 0;
    if (m == 0) val = f2bf(g_sh[sl]);
    else if (m == 1) val = f2bf(g_sh[sl] * sp_sh[sl]);
    gspF[(size_t)b * GSP_STRIDE + (size_t)((t0 >> 4) + cchunk) * 512 + within] = val;
  }
}

// ---- hot-loop macros (compile-time buffer selection; _Pragma keeps unrolls) ----
#define PRE1(KK, VV, GG, S) {                                                         \
  const unsigned short* kp_ = eFj + (size_t)((S) * 8) * 512 + l * 8;                  \
  _Pragma("unroll") for (int u = 0; u < 8; u++)                                       \
    KK[u] = *(const short8*)(kp_ + u * 512);                                          \
  _Pragma("unroll") for (int u = 0; u < 8; u++)                                       \
    VV[u] = *(const short8*)(eTj + (size_t)((u >> 1) * 64 + (S) * 2 + (u & 1)) * 512 + l * 8); \
  GG[0] = *(const short8*)(gFj + (size_t)((S) * 2) * 512 + l * 8);                    \
  GG[1] = *(const short8*)(gFj + (size_t)((S) * 2 + 1) * 512 + l * 8);                \
}

#define PRE2(KK, GG, S) {                                                             \
  const unsigned short* kp_ = eFi + (size_t)((S) * 8) * 512 + l * 8;                  \
  _Pragma("unroll") for (int u = 0; u < 8; u++)                                       \
    KK[u] = *(const short8*)(kp_ + u * 512);                                          \
  GG[0] = *(const short8*)(gFi + (size_t)((S) * 2) * 512 + l * 8);                    \
  GG[1] = *(const short8*)(gFi + (size_t)((S) * 2 + 1) * 512 + l * 8);                \
}

#define QK_CHAINS(KK, QQ)                                                             \
  f32x16 ca_ = __builtin_amdgcn_mfma_f32_32x32x16_bf16(KK[0], QQ[0], Z, 0, 0, 0);     \
  f32x16 cb_ = __builtin_amdgcn_mfma_f32_32x32x16_bf16(KK[1], QQ[1], Z, 0, 0, 0);     \
  ca_ = __builtin_amdgcn_mfma_f32_32x32x16_bf16(KK[2], QQ[2], ca_, 0, 0, 0);          \
  cb_ = __builtin_amdgcn_mfma_f32_32x32x16_bf16(KK[3], QQ[3], cb_, 0, 0, 0);          \
  ca_ = __builtin_amdgcn_mfma_f32_32x32x16_bf16(KK[4], QQ[4], ca_, 0, 0, 0);          \
  cb_ = __builtin_amdgcn_mfma_f32_32x32x16_bf16(KK[5], QQ[5], cb_, 0, 0, 0);          \
  ca_ = __builtin_amdgcn_mfma_f32_32x32x16_bf16(KK[6], QQ[6], ca_, 0, 0, 0);          \
  cb_ = __builtin_amdgcn_mfma_f32_32x32x16_bf16(KK[7], QQ[7], cb_, 0, 0, 0);

#define EXP_PACK_C2B                                                                  \
  unsigned dd_[8];                                                                    \
  _Pragma("unroll") for (int k2 = 0; k2 < 8; k2++)                                    \
    dd_[k2] = packbf(__builtin_amdgcn_exp2f(ca_[2 * k2] + cb_[2 * k2]),               \
                     __builtin_amdgcn_exp2f(ca_[2 * k2 + 1] + cb_[2 * k2 + 1]));      \
  short8 pB0_, pB1_;                                                                  \
  c2b(dd_, lh, &pB0_, &pB1_);

#define BODY1(KK, VV, GG) {                                                           \
  QK_CHAINS(KK, qf)                                                                   \
  EXP_PACK_C2B                                                                        \
  acc5 = __builtin_amdgcn_mfma_f32_32x32x16_bf16(GG[0], pB0_, acc5, 0, 0, 0);         \
  acc5 = __builtin_amdgcn_mfma_f32_32x32x16_bf16(GG[1], pB1_, acc5, 0, 0, 0);         \
  _Pragma("unroll") for (int d4 = 0; d4 < 4; d4++) {                                  \
    o[d4] = __builtin_amdgcn_mfma_f32_32x32x16_bf16(VV[2 * d4], pB0_, o[d4], 0, 0, 0);\
    o[d4] = __builtin_amdgcn_mfma_f32_32x32x16_bf16(VV[2 * d4 + 1], pB1_, o[d4], 0, 0, 0); \
  }                                                                                   \
}

#define BODY2(KK, GG) {                                                               \
  QK_CHAINS(KK, qf2)                                                                  \
  EXP_PACK_C2B                                                                        \
  acc6 = __builtin_amdgcn_mfma_f32_32x32x16_bf16(GG[0], pB0_, acc6, 0, 0, 0);         \
  acc6 = __builtin_amdgcn_mfma_f32_32x32x16_bf16(GG[1], pB1_, acc6, 0, 0, 0);         \
}

__global__ __launch_bounds__(64, 1) void tcc_main(
    const unsigned short* __restrict__ ebfF, const unsigned short* __restrict__ ebfT,
    const unsigned short* __restrict__ gspF, const float* __restrict__ steps,
    float* __restrict__ loss_acc, unsigned* __restrict__ cnt, float* __restrict__ out) {
  const int bx = blockIdx.x;           // 0..1791
  const int pair = bx >> 5;            // 56 pairs
  const int tile = bx & 31;            // 32 t-tiles of 32
  const int i = pair / 7;
  const int r = pair % 7;
  const int j = r + (r >= i ? 1 : 0);
  const int l = threadIdx.x;           // one wave per block
  const int l31 = l & 31;
  const int lh = l >> 5;
  const int tb = tile * 32;

  const unsigned short* eFi = ebfF + (size_t)i * BATCH_STRIDE;
  const unsigned short* eFj = ebfF + (size_t)j * BATCH_STRIDE;
  const unsigned short* eTj = ebfT + (size_t)j * BATCH_STRIDE;
  const unsigned short* gFi = gspF + (size_t)i * GSP_STRIDE;
  const unsigned short* gFj = gspF + (size_t)j * GSP_STRIDE;

  // Q as B-operand: fragA of e1 rows tb..tb+31 (n=t, k=d)
  short8 qf[8];
  {
    const unsigned short* qb = eFi + (size_t)((tb >> 5) * 8) * 512 + l * 8;
#pragma unroll
    for (int kc = 0; kc < 8; kc++) qf[kc] = *(const short8*)(qb + kc * 512);
  }

  const f32x16 Z = {0.f, 0.f, 0.f, 0.f, 0.f, 0.f, 0.f, 0.f,
                    0.f, 0.f, 0.f, 0.f, 0.f, 0.f, 0.f, 0.f};
  f32x16 o[4], acc5;
#pragma unroll
  for (int n2 = 0; n2 < 4; n2++) o[n2] = Z;
  acc5 = Z;

  // ---------------- phase 1: s-tile 32, 32 iters, register dbuf ----------------
  short8 kkA[8], kkB[8], vvA[8], vvB[8], ggA[2], ggB[2];
  PRE1(kkA, vvA, ggA, 0);
  for (int st = 0; st < 32; st += 2) {
    PRE1(kkB, vvB, ggB, st + 1);
    __builtin_amdgcn_sched_barrier(0);
    BODY1(kkA, vvA, ggA);
    if (st + 2 < 32) PRE1(kkA, vvA, ggA, st + 2);
    __builtin_amdgcn_sched_barrier(0);
    BODY1(kkB, vvB, ggB);
  }

  // ---- interphase: nn^T = O^T / L; phase-2 B-frags via shfl (no LDS) ----
  float Lme = acc5[0];                       // L[t] at lh=0 lanes (row 0)
  float Lo = __shfl_xor(Lme, 32, 64);
  float inv = 1.0f / (lh ? Lo : Lme);
  short8 qf2[8];
#pragma unroll
  for (int n2 = 0; n2 < 4; n2++) {
    unsigned d[8];
#pragma unroll
    for (int k2 = 0; k2 < 8; k2++)
      d[k2] = packbf(o[n2][2 * k2] * inv, o[n2][2 * k2 + 1] * inv);
    c2b(d, lh, &qf2[2 * n2], &qf2[2 * n2 + 1]);
  }

  // ---------------- phase 2: s-tile 32, 32 iters, K + gsp only ----------------
  f32x16 acc6 = Z;
  PRE2(kkA, ggA, 0);
  for (int st = 0; st < 32; st += 2) {
    PRE2(kkB, ggB, st + 1);
    __builtin_amdgcn_sched_barrier(0);
    BODY2(kkA, ggA);
    if (st + 2 < 32) PRE2(kkA, ggA, st + 2);
    __builtin_amdgcn_sched_barrier(0);
    BODY2(kkB, ggB);
  }

  // ---- epilogue: pred = tp/L2 (rows 0,1 at lh=0 lanes), MSE, fused finalize ----
  float local = 0.f;
  if (lh == 0) {
    float pred = acc6[1] / acc6[0];
    float tt = steps[i * T_ + tb + l31];
    float dd = pred - tt;
    local = dd * dd;
  }
  local = waveSum(local);
  if (l == 0) {
    atomicAdd(loss_acc, local);
    __threadfence();
    unsigned old = atomicAdd(cnt, 1u);
    if (old == (unsigned)(gridDim.x - 1)) {
      float v = atomicAdd(loss_acc, 0.0f);   // device-scope atomic read
      out[0] = v * (1.0f / (float)(NPAIR * T_));
    }
  }
}

extern "C" void kernel_launch(void* const* d_in, const int* in_sizes, int n_in,
                              void* d_out, int out_size, void* d_ws, size_t ws_size,
                              hipStream_t stream) {
  const float* embs = (const float*)d_in[0];
  const int* frame_idxs = (const int*)d_in[1];
  const int* video_len = (const int*)d_in[2];
  float* out = (float*)d_out;

  char* ws = (char*)d_ws;
  float* acc = (float*)ws;                                      // @0
  unsigned* cnt = (unsigned*)(ws + 512);                        // @512
  float* steps = (float*)(ws + 4096);                           // 8192 f32
  unsigned short* ebfF = (unsigned short*)(ws + 65536);         // 2 MB
  unsigned short* ebfT = ebfF + (size_t)8 * BATCH_STRIDE;       // 2 MB
  unsigned short* gspF = ebfT + (size_t)8 * BATCH_STRIDE;       // 512 KB

  convert_kernel<<<dim3(256), dim3(256), 0, stream>>>(embs, frame_idxs, video_len,
                                                      ebfF, ebfT, gspF, steps, acc, cnt);
  tcc_main<<<dim3(NPAIR * 32), dim3(64), 0, stream>>>(ebfF, ebfT, gspF, steps, acc, cnt, out);
}

// Round 13
// 114.594 us; speedup vs baseline: 1.5831x; 1.5831x over previous
//
#include <hip/hip_runtime.h>
#include <hip/hip_bf16.h>

// B=8, T=1024, D=128, TEMP=0.1, WEIGHT=1.0. 56 ordered pairs (i,j), i!=j.
// All-fp8 (OCP e4m3) datapath:
//   Q,K stored *SQDS; z = dot(q',k') = 2qk*log2e/12.8
//   p' = exp2(z - 6), bias in MFMA C-init, CLAMPED to 448 (R12 NaN fix: global
//   max z ~ 14 -> exp2(z-4) overflowed fp8; -6 bias + fminf is belt+suspenders)
//   V'' = g14*SQDS*e2, g14 = exp2(14 - |e|^2*NSCALE), elements CLAMPED +-440
//   L, sum(p*g*sp) via 5th V-block rows [g14; g14*sp] -> all-fp8 PV
//   Bias/2^14 factors cancel in nn = O/L and pred = tp/L2.
// Structure carried from R12 (itself from verified R10 skeleton): s-tile 64,
// 4-wave blocks, grid 448 (2 blocks/CU), LDS dbuf via global_load_lds,
// transposed-S, c2b8 shuffle transform, fused finalize.

#define T_ 1024
#define D_ 128
#define NPAIR 56
#define NSCALE 0.11271055006945026f   // (1/12.8)*log2(e)
#define SQDS 0.474785316f             // sqrt((2/12.8)*log2(e))

typedef float f32x16 __attribute__((ext_vector_type(16)));
typedef unsigned short u16x8 __attribute__((ext_vector_type(8)));

#define B8F 131072   // bytes per batch: Q/K frags (256 chunks * 512B)
#define B8T 163840   // bytes per batch: V'' frags (320 chunks: 4 d-blocks + g-block)

__device__ __forceinline__ unsigned short f2bf(float f) {
  unsigned u = __float_as_uint(f);
  u += 0x7fff + ((u >> 16) & 1);
  return (unsigned short)(u >> 16);
}
__device__ __forceinline__ float bf2f(unsigned short v) {
  return __uint_as_float(((unsigned)v) << 16);
}
__device__ __forceinline__ float clamp8(float x) {
  return fminf(fmaxf(x, -440.f), 440.f);
}
__device__ __forceinline__ unsigned pk4(float a, float b, float c, float d) {
  int w = __builtin_amdgcn_cvt_pk_fp8_f32(a, b, 0, false);
  w = __builtin_amdgcn_cvt_pk_fp8_f32(c, d, w, true);
  return (unsigned)w;
}
__device__ __forceinline__ float waveSum(float v) {
#pragma unroll
  for (int k = 32; k >= 1; k >>= 1) v += __shfl_xor(v, k, 64);
  return v;
}
__device__ __forceinline__ void stage1k(const unsigned char* g, unsigned char* lds, int lane) {
  __builtin_amdgcn_global_load_lds(
      (const __attribute__((address_space(1))) unsigned int*)(g + lane * 16),
      (__attribute__((address_space(3))) unsigned int*)lds, 16, 0, 0);
}

// fp8 C->B transform. m[0..3] = pk4 of C-regs rg 0-3 / 4-7 / 8-11 / 12-15
// (rows 4lh+0..3, 8+4lh+.., 16+.., 24+..). Output: two 16-k B chunks (8 fp8 = i64).
__device__ __forceinline__ void c2b8(const unsigned* m, int lh, long long* b0, long long* b1) {
  unsigned send0 = lh ? m[0] : m[1];
  unsigned send1 = lh ? m[2] : m[3];
  unsigned r0 = (unsigned)__shfl_xor((int)send0, 32, 64);
  unsigned r1 = (unsigned)__shfl_xor((int)send1, 32, 64);
  union { unsigned u[2]; long long ll; } x0, x1;
  x0.u[0] = lh ? r0 : m[0];  x0.u[1] = lh ? m[1] : r0;
  x1.u[0] = lh ? r1 : m[2];  x1.u[1] = lh ? m[3] : r1;
  *b0 = x0.ll; *b1 = x1.ll;
}

#define MFMA8(A, B, C) __builtin_amdgcn_mfma_f32_32x32x16_fp8_fp8((A), (B), (C), 0, 0, 0)
#define LD8(P, Q) (*(const long long*)((P) + (Q) * 512))
#define EXPC(x) fminf(__builtin_amdgcn_exp2f(x), 448.f)

// ---- convert: fp32 -> fp8 frag buffers + steps + ws init ----
__global__ __launch_bounds__(256) void convert_kernel(
    const float* __restrict__ embs, const int* __restrict__ fi,
    const int* __restrict__ vl, unsigned char* __restrict__ e8F,
    unsigned char* __restrict__ e8T, float* __restrict__ steps,
    float* __restrict__ acc, unsigned* __restrict__ cnt) {
  __shared__ unsigned short tileS[32 * 136];
  __shared__ float psum[32][8];
  __shared__ float g_sh[32], sp_sh[32];
  const int b = blockIdx.x >> 5;
  const int t0 = (blockIdx.x & 31) * 32;
  const int tid = threadIdx.x;
  const int row = tid >> 3, seg = tid & 7;

  if (blockIdx.x == 0 && tid == 0) { acc[0] = 0.f; cnt[0] = 0u; }

  const float* src = embs + (size_t)(b * T_ + t0 + row) * D_ + seg * 16;
  float4 g4[4];
#pragma unroll
  for (int k = 0; k < 4; k++) g4[k] = ((const float4*)src)[k];
  float s = 0.f;
  float fv[16];
#pragma unroll
  for (int k = 0; k < 4; k++) {
    s += g4[k].x * g4[k].x + g4[k].y * g4[k].y + g4[k].z * g4[k].z + g4[k].w * g4[k].w;
    fv[4 * k + 0] = g4[k].x * SQDS; fv[4 * k + 1] = g4[k].y * SQDS;
    fv[4 * k + 2] = g4[k].z * SQDS; fv[4 * k + 3] = g4[k].w * SQDS;
  }
  psum[row][seg] = s;

  // e8F store: chunk (t>>5)*8 + seg; lanes row (d lo 8) and 32+row (d hi 8)
  {
    unsigned char* dstA = e8F + (size_t)b * B8F + (size_t)((t0 >> 5) * 8 + seg) * 512;
    uint2 lo, hi;
    lo.x = pk4(fv[0], fv[1], fv[2], fv[3]);   lo.y = pk4(fv[4], fv[5], fv[6], fv[7]);
    hi.x = pk4(fv[8], fv[9], fv[10], fv[11]); hi.y = pk4(fv[12], fv[13], fv[14], fv[15]);
    *(uint2*)(dstA + row * 8) = lo;
    *(uint2*)(dstA + (size_t)(32 + row) * 8) = hi;
  }
  // bf16 tile for the transpose
#pragma unroll
  for (int k = 0; k < 16; k++) tileS[row * 136 + seg * 16 + k] = f2bf(fv[k]);
  __syncthreads();

  if (tid < 32) {
    float t = 0.f;
#pragma unroll
    for (int k = 0; k < 8; k++) t += psum[tid][k];
    int gr = b * T_ + t0 + tid;
    float sp = (float)fi[gr] / (float)vl[b];
    steps[gr] = sp;
    sp_sh[tid] = sp;
    g_sh[tid] = __builtin_amdgcn_exp2f(14.0f - t * NSCALE);   // g14
  }
  __syncthreads();

  // e8T d-blocks 0..3: V'' = g14 * (SQDS*e), transposed, clamped to fp8 range
  {
    const int c8 = tid >> 5;
    const int n2 = c8 & 3, scp = c8 >> 2;
    const int dd = n2 * 32 + (tid & 31);
#pragma unroll
    for (int half = 0; half < 2; half++) {
      const int lane = half * 32 + (tid & 31);
      const int sl = scp * 16 + half * 8;
      float vv[8];
#pragma unroll
      for (int jj = 0; jj < 8; jj++)
        vv[jj] = clamp8(bf2f(tileS[(sl + jj) * 136 + dd]) * g_sh[sl + jj]);
      uint2 wv;
      wv.x = pk4(vv[0], vv[1], vv[2], vv[3]);
      wv.y = pk4(vv[4], vv[5], vv[6], vv[7]);
      int c = n2 * 64 + (t0 >> 4) + scp;
      *(uint2*)(e8T + (size_t)b * B8T + (size_t)c * 512 + lane * 8) = wv;
    }
  }
  // e8T g-block (n2=4): row m=0 -> g14, m=1 -> g14*sp, else 0 (clamped)
  if (tid < 128) {
    const int sc2 = tid >> 6, lane = tid & 63;
    const int m = lane & 31, kh = lane >> 5;
    uint2 wv; wv.x = 0u; wv.y = 0u;
    if (m < 2) {
      float vv[8];
#pragma unroll
      for (int e = 0; e < 8; e++) {
        int sl = sc2 * 16 + kh * 8 + e;
        float gg = g_sh[sl];
        vv[e] = clamp8(m ? gg * sp_sh[sl] : gg);
      }
      wv.x = pk4(vv[0], vv[1], vv[2], vv[3]);
      wv.y = pk4(vv[4], vv[5], vv[6], vv[7]);
    }
    int c = 256 + (t0 >> 4) + sc2;
    *(uint2*)(e8T + (size_t)b * B8T + (size_t)c * 512 + lane * 8) = wv;
  }
}

__global__ __launch_bounds__(256, 2) void tcc_main(
    const unsigned char* __restrict__ e8F, const unsigned char* __restrict__ e8T,
    const float* __restrict__ steps, float* __restrict__ loss_acc,
    unsigned* __restrict__ cnt, float* __restrict__ out) {
  // kt 2x8192 | vt 2x10240 | gt 2x2048 = 40960 B
  __shared__ unsigned char smem[40960];
  __shared__ float blred[4];
  unsigned char* kt = smem;
  unsigned char* vt = smem + 16384;
  unsigned char* gt = smem + 36864;

  const int bx = blockIdx.x;
  const int pair = bx >> 3;
  const int tile = bx & 7;
  const int i = pair / 7;
  const int r = pair % 7;
  const int j = r + (r >= i ? 1 : 0);
  const int tid = threadIdx.x;
  const int w = tid >> 6;
  const int l = tid & 63;
  const int l31 = l & 31;
  const int lh = l >> 5;
  const int tb = tile * 128 + w * 32;

  const unsigned char* eFi = e8F + (size_t)i * B8F;
  const unsigned char* eFj = e8F + (size_t)j * B8F;
  const unsigned char* eTj = e8T + (size_t)j * B8T;
  const unsigned char* eTi = e8T + (size_t)i * B8T;

  // Q fp8 B-operand chunks (n=t, k=d)
  long long qf8[8];
  {
    const unsigned char* qb = eFi + (size_t)((tb >> 5) * 8) * 512 + l * 8;
#pragma unroll
    for (int kc = 0; kc < 8; kc++) qf8[kc] = LD8(qb, kc);
  }

  const f32x16 Z = {0.f, 0.f, 0.f, 0.f, 0.f, 0.f, 0.f, 0.f,
                    0.f, 0.f, 0.f, 0.f, 0.f, 0.f, 0.f, 0.f};
  const f32x16 CM6 = {-6.f, -6.f, -6.f, -6.f, -6.f, -6.f, -6.f, -6.f,
                      -6.f, -6.f, -6.f, -6.f, -6.f, -6.f, -6.f, -6.f};
  f32x16 o[5];   // o[0..3]=O^T d-blocks, o[4]=g-block (row0=L')
#pragma unroll
  for (int n2 = 0; n2 < 5; n2++) o[n2] = Z;

  // ---------------- phase 1: s-tile 64, 16 iterations ----------------
  // prologue: wave w stages K units 2w,2w+1; V units w, w+4, (w<2: 8+w)
  stage1k(eFj + (size_t)(2 * w) * 1024, kt + (2 * w) * 1024, l);
  stage1k(eFj + (size_t)(2 * w + 1) * 1024, kt + (2 * w + 1) * 1024, l);
#pragma unroll
  for (int u = 0; u < 3; u++) {
    int vu = w + 4 * u;
    if (vu < 10) {
      int n2v = vu >> 1, sh = vu & 1;
      stage1k(eTj + (size_t)(n2v * 32 + sh) * 1024, vt + vu * 1024, l);
    }
  }
  __syncthreads();

  for (int st = 0; st < 16; st++) {
    const int cur = st & 1, nxt = cur ^ 1;
    if (st < 15) {
      const int s1 = st + 1;
      stage1k(eFj + (size_t)(8 * s1 + 2 * w) * 1024, kt + nxt * 8192 + (2 * w) * 1024, l);
      stage1k(eFj + (size_t)(8 * s1 + 2 * w + 1) * 1024, kt + nxt * 8192 + (2 * w + 1) * 1024, l);
#pragma unroll
      for (int u = 0; u < 3; u++) {
        int vu = w + 4 * u;
        if (vu < 10) {
          int n2v = vu >> 1, sh = vu & 1;
          stage1k(eTj + (size_t)(n2v * 32 + s1 * 2 + sh) * 1024, vt + nxt * 10240 + vu * 1024, l);
        }
      }
    }
    __builtin_amdgcn_sched_barrier(0);

    const unsigned char* kb = kt + cur * 8192 + l * 8;
    const unsigned char* vb = vt + cur * 10240 + l * 8;

    // QK: one 8-deep chain per s-block (C-init = -6 bias)
    f32x16 ca0 = MFMA8(LD8(kb, 0), qf8[0], CM6);
    f32x16 ca1 = MFMA8(LD8(kb, 8), qf8[0], CM6);
#pragma unroll
    for (int dc = 1; dc < 8; dc++) {
      ca0 = MFMA8(LD8(kb, dc), qf8[dc], ca0);
      ca1 = MFMA8(LD8(kb, 8 + dc), qf8[dc], ca1);
    }
    unsigned m0[4], m1[4];
#pragma unroll
    for (int k2 = 0; k2 < 4; k2++) {
      m0[k2] = pk4(EXPC(ca0[4 * k2]), EXPC(ca0[4 * k2 + 1]),
                   EXPC(ca0[4 * k2 + 2]), EXPC(ca0[4 * k2 + 3]));
      m1[k2] = pk4(EXPC(ca1[4 * k2]), EXPC(ca1[4 * k2 + 1]),
                   EXPC(ca1[4 * k2 + 2]), EXPC(ca1[4 * k2 + 3]));
    }
    long long pB[4];
    c2b8(m0, lh, &pB[0], &pB[1]);
    c2b8(m1, lh, &pB[2], &pB[3]);
#pragma unroll
    for (int n2 = 0; n2 < 5; n2++)
#pragma unroll
      for (int sc = 0; sc < 4; sc++)
        o[n2] = MFMA8(LD8(vb, n2 * 4 + sc), pB[sc], o[n2]);
    __syncthreads();
  }

  // stage phase-2 tile 0 (K units 2w,2w+1; g unit w for w<2)
  stage1k(eFi + (size_t)(2 * w) * 1024, kt + (2 * w) * 1024, l);
  stage1k(eFi + (size_t)(2 * w + 1) * 1024, kt + (2 * w + 1) * 1024, l);
  if (w < 2) stage1k(eTi + (size_t)(128 + w) * 1024, gt + w * 1024, l);

  // ---- interphase: nn^T = O^T / L'; fp8 B-frags via shfl ----
  float Lme = o[4][0];
  float Lo = __shfl_xor(Lme, 32, 64);
  float inv = 1.0f / (lh ? Lo : Lme);
  long long qf2[8];
#pragma unroll
  for (int n2 = 0; n2 < 4; n2++) {
    unsigned mm[4];
#pragma unroll
    for (int k2 = 0; k2 < 4; k2++)
      mm[k2] = pk4(o[n2][4 * k2] * inv, o[n2][4 * k2 + 1] * inv,
                   o[n2][4 * k2 + 2] * inv, o[n2][4 * k2 + 3] * inv);
    c2b8(mm, lh, &qf2[2 * n2], &qf2[2 * n2 + 1]);
  }
  f32x16 acc6 = Z;
  __syncthreads();

  // ---------------- phase 2: s-tile 64, 16 iterations, K + g-block ----------------
  for (int st = 0; st < 16; st++) {
    const int cur = st & 1, nxt = cur ^ 1;
    if (st < 15) {
      const int s1 = st + 1;
      stage1k(eFi + (size_t)(8 * s1 + 2 * w) * 1024, kt + nxt * 8192 + (2 * w) * 1024, l);
      stage1k(eFi + (size_t)(8 * s1 + 2 * w + 1) * 1024, kt + nxt * 8192 + (2 * w + 1) * 1024, l);
      if (w < 2) stage1k(eTi + (size_t)(128 + s1 * 2 + w) * 1024, gt + nxt * 2048 + w * 1024, l);
    }
    __builtin_amdgcn_sched_barrier(0);

    const unsigned char* kb = kt + cur * 8192 + l * 8;
    const unsigned char* gb = gt + cur * 2048 + l * 8;

    f32x16 ca0 = MFMA8(LD8(kb, 0), qf2[0], CM6);
    f32x16 ca1 = MFMA8(LD8(kb, 8), qf2[0], CM6);
#pragma unroll
    for (int dc = 1; dc < 8; dc++) {
      ca0 = MFMA8(LD8(kb, dc), qf2[dc], ca0);
      ca1 = MFMA8(LD8(kb, 8 + dc), qf2[dc], ca1);
    }
    unsigned m0[4], m1[4];
#pragma unroll
    for (int k2 = 0; k2 < 4; k2++) {
      m0[k2] = pk4(EXPC(ca0[4 * k2]), EXPC(ca0[4 * k2 + 1]),
                   EXPC(ca0[4 * k2 + 2]), EXPC(ca0[4 * k2 + 3]));
      m1[k2] = pk4(EXPC(ca1[4 * k2]), EXPC(ca1[4 * k2 + 1]),
                   EXPC(ca1[4 * k2 + 2]), EXPC(ca1[4 * k2 + 3]));
    }
    long long pB[4];
    c2b8(m0, lh, &pB[0], &pB[1]);
    c2b8(m1, lh, &pB[2], &pB[3]);
#pragma unroll
    for (int sc = 0; sc < 4; sc++)
      acc6 = MFMA8(LD8(gb, sc), pB[sc], acc6);
    __syncthreads();
  }

  // ---- epilogue: pred = tp/L2 (rows 0,1 at lh=0), MSE, fused finalize ----
  float local = 0.f;
  if (lh == 0) {
    float pred = acc6[1] / acc6[0];
    float tt = steps[i * T_ + tb + l31];
    float dd = pred - tt;
    local = dd * dd;
  }
  local = waveSum(local);
  if (l == 0) blred[w] = local;
  __syncthreads();
  if (tid == 0) {
    atomicAdd(loss_acc, blred[0] + blred[1] + blred[2] + blred[3]);
    __threadfence();
    unsigned old = atomicAdd(cnt, 1u);
    if (old == (unsigned)(gridDim.x - 1)) {
      float v = atomicAdd(loss_acc, 0.0f);
      out[0] = v * (1.0f / (float)(NPAIR * T_));
    }
  }
}

extern "C" void kernel_launch(void* const* d_in, const int* in_sizes, int n_in,
                              void* d_out, int out_size, void* d_ws, size_t ws_size,
                              hipStream_t stream) {
  const float* embs = (const float*)d_in[0];
  const int* frame_idxs = (const int*)d_in[1];
  const int* video_len = (const int*)d_in[2];
  float* out = (float*)d_out;

  char* ws = (char*)d_ws;
  float* acc = (float*)ws;                                  // @0
  unsigned* cnt = (unsigned*)(ws + 512);                    // @512
  float* steps = (float*)(ws + 4096);                       // 8192 f32
  unsigned char* e8F = (unsigned char*)(ws + 65536);        // 1 MB
  unsigned char* e8T = e8F + (size_t)8 * B8F;               // 1.25 MB

  convert_kernel<<<dim3(256), dim3(256), 0, stream>>>(embs, frame_idxs, video_len,
                                                      e8F, e8T, steps, acc, cnt);
  tcc_main<<<dim3(NPAIR * 8), dim3(256), 0, stream>>>(e8F, e8T, steps, acc, cnt, out);
}